// Round 1
// baseline (207.162 us; speedup 1.0000x reference)
//
#include <hip/hip_runtime.h>
#include <stdint.h>

#define T 4096
#define E 64
#define NBH 32
#define W 4                    // windows per strip (block)
#define LDK 136                // LDS row stride (bf16 elems): 16B-aligned rows, <=2-way banks
#define CHUNK_KK (128*LDK)     // elems
#define CHUNK_VT (64*LDK)
#define BUF_ELEMS (CHUNK_KK + CHUNK_VT)   // 26112 elems = 52224 B
#define PW_ELEMS (16*LDK)                 // per-wave P scratch, 2176 elems
#define SMEM_BYTES ((2*BUF_ELEMS + 8*PW_ELEMS)*2)   // 139264 B -> 1 block/CU

typedef __attribute__((ext_vector_type(8))) short short8;
typedef __attribute__((ext_vector_type(4))) short short4v;
typedef __attribute__((ext_vector_type(4))) float f32x4;

__device__ __forceinline__ short f2bf(float x) {
  unsigned u = __float_as_uint(x);
  u += 0x7fffu + ((u >> 16) & 1u);   // round-to-nearest-even
  return (short)(u >> 16);
}

// Barrier that does NOT drain vmcnt: staged global loads stay in flight.
// (__syncthreads would emit s_waitcnt vmcnt(0) and kill the async pipeline.)
__device__ __forceinline__ void block_sync_lds() {
  asm volatile("s_waitcnt lgkmcnt(0)" ::: "memory");
  __builtin_amdgcn_s_barrier();
  asm volatile("" ::: "memory");
}

// per-thread staging registers for one K/Kr/V chunk (128 keys)
struct ChunkStage { float4 sk[8]; float sv[16]; };

__device__ __forceinline__ void chunk_issue(ChunkStage& st,
    const float* __restrict__ k, const float* __restrict__ kr,
    const float* __restrict__ v, size_t rowbase, int tid, int wid, int lane) {
#pragma unroll
  for (int m = 0; m < 2; ++m) {
    const float* src = m ? kr : k;
#pragma unroll
    for (int it = 0; it < 4; ++it) {
      int idx = it * 512 + tid;
      st.sk[m * 4 + it] = *(const float4*)(src + (rowbase + (idx >> 4)) * E + (idx & 15) * 4);
    }
  }
  const float* vp = v + (rowbase + wid * 16) * E + lane;   // lane = e, 16 t-rows
#pragma unroll
  for (int i = 0; i < 16; ++i) st.sv[i] = vp[(size_t)i * E];
}

__device__ __forceinline__ void chunk_commit(const ChunkStage& st,
    short* __restrict__ KK, short* __restrict__ Vt, int tid, int wid, int lane) {
#pragma unroll
  for (int m = 0; m < 2; ++m) {
#pragma unroll
    for (int it = 0; it < 4; ++it) {
      int idx = it * 512 + tid;
      float4 f = st.sk[m * 4 + it];
      short4v h = { f2bf(f.x), f2bf(f.y), f2bf(f.z), f2bf(f.w) };
      *(short4v*)(KK + (idx >> 4) * LDK + m * 64 + (idx & 15) * 4) = h;
    }
  }
#pragma unroll
  for (int rq = 0; rq < 4; ++rq) {
    short4v h = { f2bf(st.sv[rq*4+0]), f2bf(st.sv[rq*4+1]),
                  f2bf(st.sv[rq*4+2]), f2bf(st.sv[rq*4+3]) };
    *(short4v*)(Vt + lane * LDK + wid * 16 + rq * 4) = h;
  }
}

__device__ __forceinline__ void q_issue(float4* sq,
    const float* __restrict__ q, const float* __restrict__ qr,
    size_t rbase, int w, int wid, int li, int lg) {
  const size_t qrow = rbase + (size_t)w * 128 + wid * 16 + li;
#pragma unroll
  for (int kt = 0; kt < 4; ++kt) {
    const float* sp = (kt < 2 ? q : qr) + qrow * E + (kt & 1) * 32 + lg * 8;
    sq[kt * 2 + 0] = *(const float4*)sp;
    sq[kt * 2 + 1] = *(const float4*)(sp + 4);
  }
}

__device__ __forceinline__ void q_commit(const float4* sq, short8* aF) {
#pragma unroll
  for (int kt = 0; kt < 4; ++kt) {
    float4 f0 = sq[kt * 2], f1 = sq[kt * 2 + 1];
    short8 a;
    a[0]=f2bf(f0.x*0.125f); a[1]=f2bf(f0.y*0.125f); a[2]=f2bf(f0.z*0.125f); a[3]=f2bf(f0.w*0.125f);
    a[4]=f2bf(f1.x*0.125f); a[5]=f2bf(f1.y*0.125f); a[6]=f2bf(f1.z*0.125f); a[7]=f2bf(f1.w*0.125f);
    aF[kt] = a;
  }
}

// One block per (strip of 4 windows, bh). 8 waves x 16 q-rows per window.
// Online softmax over the two 128-key halves (back chunk, then current chunk):
//   h0: S vs c_{j-1} (no causal mask), m0/l0, P->scratch, PV accumulate
//   barrier1 (lgkm only)  -> back buffer retired
//   commit staged c_{j+1} into back slots (overlaps h1); issue c_{j+2} + Q_{j+1}
//   h1: S vs c_j (causal), rescale O/l by exp(m0-m), P->scratch, PV accumulate
//   store O/l; q_commit; barrier2 (lgkm only)
// vmcnt is never drained at barriers: staged loads are in flight ~1 full window.
__global__ __launch_bounds__(512, 2)
void la_attn(const float* __restrict__ qg, const float* __restrict__ kg,
             const float* __restrict__ qrg, const float* __restrict__ krg,
             const float* __restrict__ vg, float* __restrict__ outg) {
  extern __shared__ short smem[];

  const int strip = blockIdx.x, bh = blockIdx.y;
  const int w0 = strip * W;
  const int tid = threadIdx.x;
  const int wid = tid >> 6, lane = tid & 63;
  const int li = lane & 15, lg = lane >> 4;
  const size_t rbase = (size_t)bh * T;
  const int rowb = wid * 16 + lg * 4;

  // dedicated per-wave P scratch (no longer aliases the K buffers -> no Ba barrier)
  short* PW = smem + 2 * BUF_ELEMS + wid * PW_ELEMS;
  const int pxor_w = lg << 4;          // write swizzle: row>>2 == lg (rows lg*4+r)
  const int pxor_r = (li >> 2) << 4;   // read swizzle: row == li

  short8 aF[4];
  ChunkStage st;   // persistent staging: chunk c_{j+1} in flight

  // ---- prologue: stage c_{-1} (if any) + c_0; Q window 0; issue c_1 ----
  {
    ChunkStage sm1, s0;
    float4 sq[8];
    if (w0 > 0) chunk_issue(sm1, kg, krg, vg, rbase + (size_t)(w0 - 1) * 128, tid, wid, lane);
    chunk_issue(s0, kg, krg, vg, rbase + (size_t)w0 * 128, tid, wid, lane);
    q_issue(sq, qg, qrg, rbase, w0, wid, li, lg);
    if (w0 > 0) chunk_commit(sm1, smem + BUF_ELEMS, smem + BUF_ELEMS + CHUNK_KK, tid, wid, lane);
    chunk_commit(s0, smem, smem + CHUNK_KK, tid, wid, lane);
    q_commit(sq, aF);
    chunk_issue(st, kg, krg, vg, rbase + (size_t)(w0 + 1) * 128, tid, wid, lane);
  }
  block_sync_lds();

  for (int j = 0; j < W; ++j) {
    short* bufb = smem + ((j + 1) & 1) * BUF_ELEMS;   // backward chunk c_{j-1}
    short* bufc = smem + (j & 1) * BUF_ELEMS;         // current chunk c_j
    short* KKback = bufb;       short* Vtback = bufb + CHUNK_KK;
    short* KKcur  = bufc;       short* Vtcur  = bufc + CHUNK_KK;
    const bool skipback = (w0 == 0 && j == 0);   // block-uniform: padding chunk

    float m[4], l[4];
    f32x4 O[4] = {{0,0,0,0},{0,0,0,0},{0,0,0,0},{0,0,0,0}};
#pragma unroll
    for (int r = 0; r < 4; ++r) { m[r] = -1e30f; l[r] = 0.f; }

    // ---- h0: backward half (no causal mask) ----
    if (!skipback) {
      f32x4 S[8];
#pragma unroll
      for (int ct = 0; ct < 8; ++ct) {
        f32x4 acc = {0.f, 0.f, 0.f, 0.f};
        const short* kb = KKback + (ct * 16 + li) * LDK + lg * 8;
#pragma unroll
        for (int kt = 0; kt < 4; ++kt)
          acc = __builtin_amdgcn_mfma_f32_16x16x32_bf16(aF[kt], *(const short8*)(kb + kt * 32), acc, 0, 0, 0);
        S[ct] = acc;
      }
#pragma unroll
      for (int r = 0; r < 4; ++r) {
        float mx = S[0][r];
#pragma unroll
        for (int ct = 1; ct < 8; ++ct) mx = fmaxf(mx, S[ct][r]);
        mx = fmaxf(mx, __shfl_xor(mx, 1));
        mx = fmaxf(mx, __shfl_xor(mx, 2));
        mx = fmaxf(mx, __shfl_xor(mx, 4));
        mx = fmaxf(mx, __shfl_xor(mx, 8));
        float sm = 0.f;
#pragma unroll
        for (int ct = 0; ct < 8; ++ct) {
          float e = __expf(S[ct][r] - mx);
          S[ct][r] = e;
          sm += e;
        }
        sm += __shfl_xor(sm, 1);
        sm += __shfl_xor(sm, 2);
        sm += __shfl_xor(sm, 4);
        sm += __shfl_xor(sm, 8);
        m[r] = mx; l[r] = sm;
      }
#pragma unroll
      for (int cc = 0; cc < 8; ++cc)
#pragma unroll
        for (int r = 0; r < 4; ++r)
          PW[(lg * 4 + r) * LDK + ((cc * 16 + li) ^ pxor_w)] = f2bf(S[cc][r]);
#pragma unroll
      for (int kt = 0; kt < 4; ++kt) {
        short8 aP = *(const short8*)(PW + li * LDK + ((kt * 32 + lg * 8) ^ pxor_r));
#pragma unroll
        for (int nt = 0; nt < 4; ++nt) {
          short8 b = *(const short8*)(Vtback + (nt * 16 + li) * LDK + kt * 32 + lg * 8);
          O[nt] = __builtin_amdgcn_mfma_f32_16x16x32_bf16(aP, b, O[nt], 0, 0, 0);
        }
      }
    }

    block_sync_lds();   // barrier1: back buffer fully retired (lgkm only, vmcnt live)

    // ---- commit staged c_{j+1} (issued one window ago) into retired slots;
    //      immediately issue c_{j+2} + Q_{j+1} (in flight across barrier2) ----
    const bool have_next = (j + 1 < W);
    if (have_next) chunk_commit(st, KKback, Vtback, tid, wid, lane);
    float4 sq[8];
    if (j + 2 < W) chunk_issue(st, kg, krg, vg, rbase + (size_t)(w0 + j + 2) * 128, tid, wid, lane);
    if (have_next) q_issue(sq, qg, qrg, rbase, w0 + j + 1, wid, li, lg);
    asm volatile("" ::: "memory");   // pin issue point: loads must not sink into h1

    // ---- h1: current half (causal mask) with online rescale ----
    {
      f32x4 S[8];
#pragma unroll
      for (int ct = 0; ct < 8; ++ct) {
        f32x4 acc = {0.f, 0.f, 0.f, 0.f};
        const short* kb = KKcur + (ct * 16 + li) * LDK + lg * 8;
#pragma unroll
        for (int kt = 0; kt < 4; ++kt)
          acc = __builtin_amdgcn_mfma_f32_16x16x32_bf16(aF[kt], *(const short8*)(kb + kt * 32), acc, 0, 0, 0);
        S[ct] = acc;
      }
#pragma unroll
      for (int r = 0; r < 4; ++r) {
        const int qi = rowb + r;
#pragma unroll
        for (int ct = 0; ct < 8; ++ct) {
          int jj = ct * 16 + li;                // local key pos 0..127
          if (jj > qi) S[ct][r] = -1e30f;
        }
        float mx = S[0][r];
#pragma unroll
        for (int ct = 1; ct < 8; ++ct) mx = fmaxf(mx, S[ct][r]);
        mx = fmaxf(mx, __shfl_xor(mx, 1));
        mx = fmaxf(mx, __shfl_xor(mx, 2));
        mx = fmaxf(mx, __shfl_xor(mx, 4));
        mx = fmaxf(mx, __shfl_xor(mx, 8));
        float mn = fmaxf(m[r], mx);
        float f = __expf(m[r] - mn);            // skipback: exp(-1e30-mn) -> 0
        float sm = 0.f;
#pragma unroll
        for (int ct = 0; ct < 8; ++ct) {
          float e = __expf(S[ct][r] - mn);
          S[ct][r] = e;
          sm += e;
        }
        sm += __shfl_xor(sm, 1);
        sm += __shfl_xor(sm, 2);
        sm += __shfl_xor(sm, 4);
        sm += __shfl_xor(sm, 8);
        l[r] = l[r] * f + sm;
        m[r] = mn;
#pragma unroll
        for (int nt = 0; nt < 4; ++nt) O[nt][r] *= f;
      }
#pragma unroll
      for (int cc = 0; cc < 8; ++cc)
#pragma unroll
        for (int r = 0; r < 4; ++r)
          PW[(lg * 4 + r) * LDK + ((cc * 16 + li) ^ pxor_w)] = f2bf(S[cc][r]);
#pragma unroll
      for (int kt = 0; kt < 4; ++kt) {
        short8 aP = *(const short8*)(PW + li * LDK + ((kt * 32 + lg * 8) ^ pxor_r));
#pragma unroll
        for (int nt = 0; nt < 4; ++nt) {
          short8 b = *(const short8*)(Vtcur + (nt * 16 + li) * LDK + kt * 32 + lg * 8);
          O[nt] = __builtin_amdgcn_mfma_f32_16x16x32_bf16(aP, b, O[nt], 0, 0, 0);
        }
      }
    }

    // ---- store this window's output (stores stay in flight; nobody waits) ----
    float* op = outg + (rbase + (size_t)(w0 + j) * 128 + rowb) * E;
#pragma unroll
    for (int r = 0; r < 4; ++r) {
      float linv = 1.f / l[r];
#pragma unroll
      for (int nt = 0; nt < 4; ++nt)
        op[(size_t)r * E + nt * 16 + li] = O[nt][r] * linv;
    }

    if (have_next) q_commit(sq, aF);
    block_sync_lds();   // barrier2: committed chunk visible for next window
  }
}

extern "C" void kernel_launch(void* const* d_in, const int* in_sizes, int n_in,
                              void* d_out, int out_size, void* d_ws, size_t ws_size,
                              hipStream_t stream) {
  const float* q  = (const float*)d_in[0];
  const float* k  = (const float*)d_in[1];
  const float* qr = (const float*)d_in[2];
  const float* kr = (const float*)d_in[3];
  const float* v  = (const float*)d_in[4];
  float* out = (float*)d_out;
  la_attn<<<dim3(8, NBH), 512, SMEM_BYTES, stream>>>(q, k, qr, kr, v, out);
}